// Round 6
// baseline (358.098 us; speedup 1.0000x reference)
//
#include <hip/hip_runtime.h>
#include <hip/hip_bf16.h>
#include <math.h>

#define NN 65536          // nodes
#define NE 196608         // edges (without self loops)
#define ET (NE + NN)      // edges + self loops = 262144
#define NG 2048           // graphs
#define FIN 9
#define DD 128
#define H1 10
#define KK (H1 * DD)      // 1280
#define LRS 0.2f

typedef __attribute__((ext_vector_type(8))) short short8v;
typedef __attribute__((ext_vector_type(4))) float f32x4;

__device__ __forceinline__ float lrelu(float v) { return v >= 0.f ? v : LRS * v; }
__device__ __forceinline__ float eluf(float v)  { return v > 0.f ? v : expm1f(v); }

// float atomic max via int max (non-negative) / uint min (negative).
__device__ __forceinline__ void atomicMaxF(float* addr, float v) {
    if (__float_as_int(v) >= 0) {
        atomicMax((int*)addr, __float_as_int(v));
    } else {
        atomicMin((unsigned int*)addr, __float_as_uint(v));
    }
}

// float -> bf16 round-to-nearest-even (3 int ops, no libcall)
__device__ __forceinline__ unsigned short f2bf(float f) {
    unsigned int u = __float_as_uint(f);
    u += 0x7FFFu + ((u >> 16) & 1u);
    return (unsigned short)(u >> 16);
}

// ---- kernel 1: fold W1 into per-head 9-dim logit vectors --------------------
__global__ void prep_kernel(const float* __restrict__ W1,
                            const float* __restrict__ a_src1,
                            const float* __restrict__ a_dst1,
                            float* __restrict__ ws1, float* __restrict__ wd1) {
    int t = threadIdx.x;
    if (t >= FIN * H1) return;
    int f = t / H1, h = t - f * H1;
    float s = 0.f, d = 0.f;
    for (int c = 0; c < DD; ++c) {
        float w = W1[f * KK + h * DD + c];
        s = fmaf(w, a_src1[h * DD + c], s);
        d = fmaf(w, a_dst1[h * DD + c], d);
    }
    ws1[t] = s;
    wd1[t] = d;
}

// ---- pack W2 (1280x128 fp32) into bf16 B-fragment layout --------------------
__global__ void packW2_kernel(const float* __restrict__ W2, unsigned short* __restrict__ W2p) {
    int idx = blockIdx.x * 256 + threadIdx.x;
    if (idx >= KK * DD) return;
    int r  = idx & 7;
    int l  = (idx >> 3) & 63;
    int nt = (idx >> 9) & 7;
    int kt = idx >> 12;
    int k = kt * 32 + ((l >> 4) << 3) + r;
    int n = nt * 16 + (l & 15);
    W2p[idx] = f2bf(W2[(size_t)k * DD + n]);
}

// ---- kernel 2: per-node logits + zero deg + pooled init ---------------------
__global__ void alpha1_kernel(const float* __restrict__ x,
                              const float* __restrict__ ws1,
                              const float* __restrict__ wd1,
                              float* __restrict__ as1, float* __restrict__ ad1,
                              int* __restrict__ deg, float* __restrict__ pooled) {
    int n = blockIdx.x * 256 + threadIdx.x;
    if (n >= NN) return;
    float xv[FIN];
#pragma unroll
    for (int f = 0; f < FIN; ++f) xv[f] = x[(size_t)n * FIN + f];
#pragma unroll
    for (int h = 0; h < H1; ++h) {
        float s = 0.f, d = 0.f;
#pragma unroll
        for (int f = 0; f < FIN; ++f) {
            s = fmaf(xv[f], ws1[f * H1 + h], s);
            d = fmaf(xv[f], wd1[f * H1 + h], d);
        }
        as1[n * H1 + h] = s;
        ad1[n * H1 + h] = d;
    }
    deg[n] = 0;
    // pooled has NG*DD = 4*NN entries
    *(float4*)&pooled[(size_t)n * 4] = make_float4(-INFINITY, -INFINITY, -INFINITY, -INFINITY);
}

// ---- CSR build: count / scan / scatter --------------------------------------
__global__ void count_kernel(const int* __restrict__ ei, int* __restrict__ deg) {
    int e = blockIdx.x * 256 + threadIdx.x;
    if (e >= ET) return;
    int d = (e < NE) ? ei[NE + e] : e - NE;
    atomicAdd(&deg[d], 1);
}

__global__ __launch_bounds__(1024) void scan_kernel(const int* __restrict__ deg,
                                                    int* __restrict__ rowptr,
                                                    int* __restrict__ cursor) {
    __shared__ int part[1024];
    int t = threadIdx.x;
    int sum = 0;
    for (int i = 0; i < 64; ++i) sum += deg[t * 64 + i];
    part[t] = sum;
    __syncthreads();
    for (int off = 1; off < 1024; off <<= 1) {
        int v = (t >= off) ? part[t - off] : 0;
        __syncthreads();
        part[t] += v;
        __syncthreads();
    }
    int run = (t == 0) ? 0 : part[t - 1];
    for (int i = 0; i < 64; ++i) {
        int idx = t * 64 + i;
        rowptr[idx] = run;
        cursor[idx] = run;
        run += deg[idx];
    }
    if (t == 1023) rowptr[NN] = run;
}

__global__ void scatter_kernel(const int* __restrict__ ei, int* __restrict__ cursor,
                               int* __restrict__ elist) {
    int e = blockIdx.x * 256 + threadIdx.x;
    if (e >= ET) return;
    int s, d;
    if (e < NE) { s = ei[e]; d = ei[NE + e]; } else { s = d = e - NE; }
    int pos = atomicAdd(&cursor[d], 1);
    elist[pos] = s;
}

// ---- layer-1 aggregation: gather-side, ONLINE softmax (single pass) ---------
__global__ void agg1_kernel(const int* __restrict__ rowptr, const int* __restrict__ elist,
                            const float* __restrict__ x,
                            const float* __restrict__ as1, const float* __restrict__ ad1,
                            float* __restrict__ xaggn) {
    int idx = blockIdx.x * 256 + threadIdx.x;     // NN*H1
    if (idx >= NN * H1) return;
    int d = idx / H1, h = idx - d * H1;
    int beg = rowptr[d], end = rowptr[d + 1];
    float adh = ad1[d * H1 + h];
    float m = -INFINITY, den = 0.f;
    float xa[FIN] = {};
    for (int j = beg; j < end; ++j) {
        int s = elist[j];
        float v = lrelu(as1[s * H1 + h] + adh);
        if (v > m) {
            float sc = __expf(m - v);
            den *= sc;
#pragma unroll
            for (int f = 0; f < FIN; ++f) xa[f] *= sc;
            m = v;
        }
        float ex = __expf(v - m);
        den += ex;
        const float* xs = &x[(size_t)s * FIN];
#pragma unroll
        for (int f = 0; f < FIN; ++f) xa[f] = fmaf(ex, xs[f], xa[f]);
    }
    float inv = 1.f / (den + 1e-16f);
    float* o = &xaggn[(size_t)idx * FIN];
#pragma unroll
    for (int f = 0; f < FIN; ++f) o[f] = xa[f] * inv;
}

// ---- fused h2 = elu(xaggn@W1 + b1) @ W2 via MFMA + alpha2 epilogue ----------
// Double-buffered Xs: one barrier per K-step; build step s+1 (registers) while
// MFMA consumes step s. B-fragments prefetched at iter top. Epilogue computes
// as2/ad2 (layer-2 logits) from accumulators via shfl-reduce + LDS atomics.
__global__ __launch_bounds__(256, 4) void h2_gemm(const float* __restrict__ xaggn,
                                                  const float* __restrict__ W1,
                                                  const float* __restrict__ b1,
                                                  const unsigned short* __restrict__ W2p,
                                                  const float* __restrict__ a_src2,
                                                  const float* __restrict__ a_dst2,
                                                  float* __restrict__ h2,
                                                  float* __restrict__ as2,
                                                  float* __restrict__ ad2) {
    __shared__ float xagg_s[64 * 91];             // 23.3 KB, stride 91 (odd: conflict-free)
    __shared__ unsigned short Xs[2][64 * 64];     // 2 x 8 KB, XOR-swizzled 16B granules
    __shared__ float as_s[64], ad_s[64];
    const int t = threadIdx.x;
    const int n0 = blockIdx.x * 64;

    for (int idx = t; idx < 64 * 90; idx += 256) {
        int row = idx / 90, c = idx - row * 90;
        xagg_s[row * 91 + c] = xaggn[(size_t)n0 * 90 + idx];
    }
    if (t < 64) { as_s[t] = 0.f; ad_s[t] = 0.f; }

    const int row = t & 63;
    const int wvu = __builtin_amdgcn_readfirstlane(t >> 6);
    const int lane = t & 63;
    const int rlo = lane & 15, khi = lane >> 4;

    f32x4 acc[4][2];
#pragma unroll
    for (int mt = 0; mt < 4; ++mt)
#pragma unroll
        for (int ntl = 0; ntl < 2; ++ntl)
#pragma unroll
            for (int q = 0; q < 4; ++q) acc[mt][ntl][q] = 0.f;

    // build x1 fragment for K-step s into 8 packed bf16 pairs
    auto build = [&](int s, unsigned int pk[8]) {
        const int h = s >> 1;
        const int k0 = s << 6;
        float xa[FIN];
#pragma unroll
        for (int f = 0; f < FIN; ++f) xa[f] = xagg_s[row * 91 + h * FIN + f];
        const float* w1s = W1 + (size_t)(k0 + wvu * 16);
        const float* b1s = b1 + (k0 + wvu * 16);
        float z[16];
#pragma unroll
        for (int c = 0; c < 16; ++c) z[c] = b1s[c];
#pragma unroll
        for (int f = 0; f < FIN; ++f)
#pragma unroll
            for (int c = 0; c < 16; ++c)
                z[c] = fmaf(xa[f], w1s[(size_t)f * KK + c], z[c]);
#pragma unroll
        for (int p = 0; p < 8; ++p) {
            float lo = z[2 * p], hi = z[2 * p + 1];
            lo = lo > 0.f ? lo : __expf(lo) - 1.f;
            hi = hi > 0.f ? hi : __expf(hi) - 1.f;
            pk[p] = (unsigned int)f2bf(lo) | ((unsigned int)f2bf(hi) << 16);
        }
    };
    auto writeXs = [&](int buf, const unsigned int pk[8]) {
#pragma unroll
        for (int j = 0; j < 2; ++j) {
            int g = wvu * 2 + j;
            uint4 v = make_uint4(pk[j * 4 + 0], pk[j * 4 + 1], pk[j * 4 + 2], pk[j * 4 + 3]);
            *(uint4*)&Xs[buf][row * 64 + ((g ^ (row & 7)) << 3)] = v;
        }
    };

    __syncthreads();                     // xagg_s staged
    unsigned int pk0[8];
    build(0, pk0);
    writeXs(0, pk0);
    __syncthreads();

    for (int s = 0; s < 20; ++s) {
        const int cur = s & 1;
        // prefetch B fragments for this step
        short8v bfr[2][2];
#pragma unroll
        for (int ks = 0; ks < 2; ++ks)
#pragma unroll
            for (int ntl = 0; ntl < 2; ++ntl) {
                const int ktabs = s * 2 + ks;
                const int nt = wvu * 2 + ntl;
                bfr[ks][ntl] = *(const short8v*)&W2p[(((size_t)ktabs * 8 + nt) * 64 + lane) * 8];
            }
        unsigned int pn[8];
        if (s < 19) build(s + 1, pn);
#pragma unroll
        for (int ks = 0; ks < 2; ++ks) {
#pragma unroll
            for (int mt = 0; mt < 4; ++mt) {
                const int row2 = mt * 16 + rlo;
                const int gk = ks * 4 + khi;
                short8v af = *(const short8v*)&Xs[cur][row2 * 64 + ((gk ^ (row2 & 7)) << 3)];
                acc[mt][0] = __builtin_amdgcn_mfma_f32_16x16x32_bf16(af, bfr[ks][0], acc[mt][0], 0, 0, 0);
                acc[mt][1] = __builtin_amdgcn_mfma_f32_16x16x32_bf16(af, bfr[ks][1], acc[mt][1], 0, 0, 0);
            }
        }
        if (s < 19) writeXs(cur ^ 1, pn);
        __syncthreads();
    }

    // C write: col = lane&15, row = (lane>>4)*4 + reg
#pragma unroll
    for (int mt = 0; mt < 4; ++mt)
#pragma unroll
        for (int ntl = 0; ntl < 2; ++ntl)
#pragma unroll
            for (int q = 0; q < 4; ++q) {
                int r2 = n0 + mt * 16 + khi * 4 + q;
                int c2 = wvu * 32 + ntl * 16 + rlo;
                h2[(size_t)r2 * DD + c2] = acc[mt][ntl][q];
            }

    // fused alpha2: as2[n] = h2[n,:]·a_src2, ad2[n] = h2[n,:]·a_dst2
    float sp[16], dp[16];
#pragma unroll
    for (int mt = 0; mt < 4; ++mt)
#pragma unroll
        for (int q = 0; q < 4; ++q) {
            float a = 0.f, b = 0.f;
#pragma unroll
            for (int ntl = 0; ntl < 2; ++ntl) {
                int col = wvu * 32 + ntl * 16 + rlo;
                float v = acc[mt][ntl][q];
                a = fmaf(v, a_src2[col], a);
                b = fmaf(v, a_dst2[col], b);
            }
            sp[mt * 4 + q] = a;
            dp[mt * 4 + q] = b;
        }
#pragma unroll
    for (int off = 1; off < 16; off <<= 1) {
#pragma unroll
        for (int i = 0; i < 16; ++i) {
            sp[i] += __shfl_xor(sp[i], off);
            dp[i] += __shfl_xor(dp[i], off);
        }
    }
    if (rlo == 0) {
#pragma unroll
        for (int mt = 0; mt < 4; ++mt)
#pragma unroll
            for (int q = 0; q < 4; ++q) {
                atomicAdd(&as_s[mt * 16 + khi * 4 + q], sp[mt * 4 + q]);
                atomicAdd(&ad_s[mt * 16 + khi * 4 + q], dp[mt * 4 + q]);
            }
    }
    __syncthreads();
    if (t < 64) {
        as2[n0 + t] = as_s[t];
        ad2[n0 + t] = ad_s[t];
    }
}

// ---- layer-2 aggregation (online softmax) + fused max-pooling ---------------
__global__ void agg2_kernel(const int* __restrict__ rowptr, const int* __restrict__ elist,
                            const float* __restrict__ h2,
                            const float* __restrict__ as2, const float* __restrict__ ad2,
                            const float* __restrict__ b2, const int* __restrict__ batch,
                            float* __restrict__ pooled) {
    int gid = blockIdx.x * 256 + threadIdx.x;
    int n = gid >> 5, lane = gid & 31;
    if (n >= NN) return;
    int beg = rowptr[n], end = rowptr[n + 1];
    float adn = ad2[n];
    float m = -INFINITY, den = 0.f;
    float4 acc = make_float4(0.f, 0.f, 0.f, 0.f);
    for (int j = beg; j < end; ++j) {
        int s = elist[j];
        float v = lrelu(as2[s] + adn);
        if (v > m) {
            float sc = __expf(m - v);
            den *= sc;
            acc.x *= sc; acc.y *= sc; acc.z *= sc; acc.w *= sc;
            m = v;
        }
        float ex = __expf(v - m);
        den += ex;
        float4 hv = *(const float4*)&h2[(size_t)s * DD + lane * 4];
        acc.x = fmaf(ex, hv.x, acc.x);
        acc.y = fmaf(ex, hv.y, acc.y);
        acc.z = fmaf(ex, hv.z, acc.z);
        acc.w = fmaf(ex, hv.w, acc.w);
    }
    float inv = 1.f / (den + 1e-16f);
    float4 bv = *(const float4*)&b2[lane * 4];
    float4 r;
    r.x = eluf(acc.x * inv + bv.x);
    r.y = eluf(acc.y * inv + bv.y);
    r.z = eluf(acc.z * inv + bv.z);
    r.w = eluf(acc.w * inv + bv.w);
    float* pg = &pooled[(size_t)batch[n] * DD + lane * 4];
    atomicMaxF(pg + 0, r.x);
    atomicMaxF(pg + 1, r.y);
    atomicMaxF(pg + 2, r.z);
    atomicMaxF(pg + 3, r.w);
}

// ---- out = relu(guard(pooled) @ Wfc + bfc) ----------------------------------
__global__ void final_kernel(const float* __restrict__ pooled, const float* __restrict__ Wfc,
                             const float* __restrict__ bfc, float* __restrict__ out) {
    int idx = blockIdx.x * 256 + threadIdx.x;   // NG*DD
    int g = idx >> 7, c = idx & 127;
    float acc = bfc[c];
#pragma unroll 8
    for (int k = 0; k < DD; ++k) {
        float p = pooled[g * DD + k];
        p = (p == -INFINITY) ? 0.f : p;
        acc = fmaf(p, Wfc[k * DD + c], acc);
    }
    out[idx] = acc > 0.f ? acc : 0.f;
}

extern "C" void kernel_launch(void* const* d_in, const int* in_sizes, int n_in,
                              void* d_out, int out_size, void* d_ws, size_t ws_size,
                              hipStream_t stream) {
    const float* x      = (const float*)d_in[0];
    const int*   ei     = (const int*)d_in[1];
    const int*   batch  = (const int*)d_in[3];
    const float* W1     = (const float*)d_in[4];
    const float* a_src1 = (const float*)d_in[5];
    const float* a_dst1 = (const float*)d_in[6];
    const float* b1     = (const float*)d_in[7];
    const float* W2     = (const float*)d_in[8];
    const float* a_src2 = (const float*)d_in[9];
    const float* a_dst2 = (const float*)d_in[10];
    const float* b2     = (const float*)d_in[11];
    const float* Wfc    = (const float*)d_in[12];
    const float* bfc    = (const float*)d_in[13];
    float* out = (float*)d_out;

    // workspace layout — ~66 MB total
    float* wsf    = (float*)d_ws;
    float* ws1    = wsf;                                   // 96
    float* wd1    = ws1 + 96;                              // 96
    float* as1    = wd1 + 96;                              // NN*H1
    float* ad1    = as1 + (size_t)NN * H1;                 // NN*H1
    float* xaggn  = ad1 + (size_t)NN * H1;                 // NN*H1*FIN
    float* h2     = xaggn + (size_t)NN * H1 * FIN;         // NN*DD
    float* as2    = h2 + (size_t)NN * DD;                  // NN
    float* ad2    = as2 + NN;                              // NN
    float* pooled = ad2 + NN;                              // NG*DD
    int*   deg    = (int*)(pooled + (size_t)NG * DD);      // NN
    int*   rowptr = deg + NN;                              // NN+1
    int*   cursor = rowptr + NN + 1;                       // NN
    int*   elist  = cursor + NN;                           // ET
    size_t off = (size_t)((char*)(elist + ET) - (char*)d_ws);
    off = (off + 15) & ~(size_t)15;
    unsigned short* W2p = (unsigned short*)((char*)d_ws + off);  // KK*DD bf16

    prep_kernel   <<<1, 128, 0, stream>>>(W1, a_src1, a_dst1, ws1, wd1);
    packW2_kernel <<<(KK * DD + 255) / 256, 256, 0, stream>>>(W2, W2p);
    alpha1_kernel <<<NN / 256, 256, 0, stream>>>(x, ws1, wd1, as1, ad1, deg, pooled);
    count_kernel  <<<(ET + 255) / 256, 256, 0, stream>>>(ei, deg);
    scan_kernel   <<<1, 1024, 0, stream>>>(deg, rowptr, cursor);
    scatter_kernel<<<(ET + 255) / 256, 256, 0, stream>>>(ei, cursor, elist);
    agg1_kernel   <<<(NN * H1 + 255) / 256, 256, 0, stream>>>(rowptr, elist, x, as1, ad1, xaggn);
    h2_gemm       <<<NN / 64, 256, 0, stream>>>(xaggn, W1, b1, W2p, a_src2, a_dst2, h2, as2, ad2);
    agg2_kernel   <<<(NN * 32) / 256, 256, 0, stream>>>(rowptr, elist, h2, as2, ad2, b2, batch, pooled);
    final_kernel  <<<(NG * DD) / 256, 256, 0, stream>>>(pooled, Wfc, bfc, out);
}

// Round 7
// 225.200 us; speedup vs baseline: 1.5901x; 1.5901x over previous
//
#include <hip/hip_runtime.h>
#include <hip/hip_bf16.h>
#include <math.h>

#define NN 65536          // nodes
#define NE 196608         // edges (without self loops)
#define ET (NE + NN)      // edges + self loops = 262144
#define NG 2048           // graphs
#define FIN 9
#define DD 128
#define H1 10
#define KK (H1 * DD)      // 1280
#define LRS 0.2f

typedef __attribute__((ext_vector_type(8))) short short8v;
typedef __attribute__((ext_vector_type(4))) float f32x4;

__device__ __forceinline__ float lrelu(float v) { return v >= 0.f ? v : LRS * v; }
__device__ __forceinline__ float eluf(float v)  { return v > 0.f ? v : expm1f(v); }

// float -> bf16 round-to-nearest-even (3 int ops, no libcall)
__device__ __forceinline__ unsigned short f2bf(float f) {
    unsigned int u = __float_as_uint(f);
    u += 0x7FFFu + ((u >> 16) & 1u);
    return (unsigned short)(u >> 16);
}

// ---- kernel 1: fold W1 into per-head 9-dim logit vectors --------------------
__global__ void prep_kernel(const float* __restrict__ W1,
                            const float* __restrict__ a_src1,
                            const float* __restrict__ a_dst1,
                            float* __restrict__ ws1, float* __restrict__ wd1) {
    int t = threadIdx.x;
    if (t >= FIN * H1) return;
    int f = t / H1, h = t - f * H1;
    float s = 0.f, d = 0.f;
    for (int c = 0; c < DD; ++c) {
        float w = W1[f * KK + h * DD + c];
        s = fmaf(w, a_src1[h * DD + c], s);
        d = fmaf(w, a_dst1[h * DD + c], d);
    }
    ws1[t] = s;
    wd1[t] = d;
}

// ---- pack W2 (1280x128 fp32) into bf16 B-fragment layout --------------------
__global__ void packW2_kernel(const float* __restrict__ W2, unsigned short* __restrict__ W2p) {
    int idx = blockIdx.x * 256 + threadIdx.x;
    if (idx >= KK * DD) return;
    int r  = idx & 7;
    int l  = (idx >> 3) & 63;
    int nt = (idx >> 9) & 7;
    int kt = idx >> 12;
    int k = kt * 32 + ((l >> 4) << 3) + r;
    int n = nt * 16 + (l & 15);
    W2p[idx] = f2bf(W2[(size_t)k * DD + n]);
}

// ---- kernel 2: per-node logits + zero deg -----------------------------------
__global__ void alpha1_kernel(const float* __restrict__ x,
                              const float* __restrict__ ws1,
                              const float* __restrict__ wd1,
                              float* __restrict__ as1, float* __restrict__ ad1,
                              int* __restrict__ deg) {
    int n = blockIdx.x * 256 + threadIdx.x;
    if (n >= NN) return;
    float xv[FIN];
#pragma unroll
    for (int f = 0; f < FIN; ++f) xv[f] = x[(size_t)n * FIN + f];
#pragma unroll
    for (int h = 0; h < H1; ++h) {
        float s = 0.f, d = 0.f;
#pragma unroll
        for (int f = 0; f < FIN; ++f) {
            s = fmaf(xv[f], ws1[f * H1 + h], s);
            d = fmaf(xv[f], wd1[f * H1 + h], d);
        }
        as1[n * H1 + h] = s;
        ad1[n * H1 + h] = d;
    }
    deg[n] = 0;
}

// ---- CSR build: count / scan / scatter --------------------------------------
__global__ void count_kernel(const int* __restrict__ ei, int* __restrict__ deg) {
    int e = blockIdx.x * 256 + threadIdx.x;
    if (e >= ET) return;
    int d = (e < NE) ? ei[NE + e] : e - NE;
    atomicAdd(&deg[d], 1);
}

__global__ __launch_bounds__(1024) void scan_kernel(const int* __restrict__ deg,
                                                    int* __restrict__ rowptr,
                                                    int* __restrict__ cursor) {
    __shared__ int part[1024];
    int t = threadIdx.x;
    int sum = 0;
    for (int i = 0; i < 64; ++i) sum += deg[t * 64 + i];
    part[t] = sum;
    __syncthreads();
    for (int off = 1; off < 1024; off <<= 1) {
        int v = (t >= off) ? part[t - off] : 0;
        __syncthreads();
        part[t] += v;
        __syncthreads();
    }
    int run = (t == 0) ? 0 : part[t - 1];
    for (int i = 0; i < 64; ++i) {
        int idx = t * 64 + i;
        rowptr[idx] = run;
        cursor[idx] = run;
        run += deg[idx];
    }
    if (t == 1023) rowptr[NN] = run;
}

__global__ void scatter_kernel(const int* __restrict__ ei, int* __restrict__ cursor,
                               int* __restrict__ elist) {
    int e = blockIdx.x * 256 + threadIdx.x;
    if (e >= ET) return;
    int s, d;
    if (e < NE) { s = ei[e]; d = ei[NE + e]; } else { s = d = e - NE; }
    int pos = atomicAdd(&cursor[d], 1);
    elist[pos] = s;
}

// ---- per-graph node ranges from the sorted batch vector ---------------------
__global__ void gptr_kernel(const int* __restrict__ batch, int* __restrict__ gptr) {
    int n = blockIdx.x * 256 + threadIdx.x;
    if (n >= NN) return;
    int bn = batch[n];
    int bp = (n == 0) ? -1 : batch[n - 1];
    for (int g = bp + 1; g <= bn; ++g) gptr[g] = n;
    if (n == NN - 1) {
        for (int g = bn + 1; g <= NG; ++g) gptr[g] = NN;
    }
}

// ---- layer-1 aggregation: gather-side, ONLINE softmax (single pass) ---------
__global__ void agg1_kernel(const int* __restrict__ rowptr, const int* __restrict__ elist,
                            const float* __restrict__ x,
                            const float* __restrict__ as1, const float* __restrict__ ad1,
                            float* __restrict__ xaggn) {
    int idx = blockIdx.x * 256 + threadIdx.x;     // NN*H1
    if (idx >= NN * H1) return;
    int d = idx / H1, h = idx - d * H1;
    int beg = rowptr[d], end = rowptr[d + 1];
    float adh = ad1[d * H1 + h];
    float m = -INFINITY, den = 0.f;
    float xa[FIN] = {};
    for (int j = beg; j < end; ++j) {
        int s = elist[j];
        float v = lrelu(as1[s * H1 + h] + adh);
        if (v > m) {
            float sc = __expf(m - v);
            den *= sc;
#pragma unroll
            for (int f = 0; f < FIN; ++f) xa[f] *= sc;
            m = v;
        }
        float ex = __expf(v - m);
        den += ex;
        const float* xs = &x[(size_t)s * FIN];
#pragma unroll
        for (int f = 0; f < FIN; ++f) xa[f] = fmaf(ex, xs[f], xa[f]);
    }
    float inv = 1.f / (den + 1e-16f);
    float* o = &xaggn[(size_t)idx * FIN];
#pragma unroll
    for (int f = 0; f < FIN; ++f) o[f] = xa[f] * inv;
}

// ---- fused h2 = elu(xaggn@W1 + b1) @ W2 via MFMA + alpha2 epilogue ----------
__global__ __launch_bounds__(256, 4) void h2_gemm(const float* __restrict__ xaggn,
                                                  const float* __restrict__ W1,
                                                  const float* __restrict__ b1,
                                                  const unsigned short* __restrict__ W2p,
                                                  const float* __restrict__ a_src2,
                                                  const float* __restrict__ a_dst2,
                                                  float* __restrict__ h2,
                                                  float* __restrict__ as2,
                                                  float* __restrict__ ad2) {
    __shared__ float xagg_s[64 * 91];             // 23.3 KB, stride 91 (odd: conflict-free)
    __shared__ unsigned short Xs[2][64 * 64];     // 2 x 8 KB, XOR-swizzled 16B granules
    __shared__ float as_s[64], ad_s[64];
    const int t = threadIdx.x;
    const int n0 = blockIdx.x * 64;

    for (int idx = t; idx < 64 * 90; idx += 256) {
        int row = idx / 90, c = idx - row * 90;
        xagg_s[row * 91 + c] = xaggn[(size_t)n0 * 90 + idx];
    }
    if (t < 64) { as_s[t] = 0.f; ad_s[t] = 0.f; }

    const int row = t & 63;
    const int wvu = __builtin_amdgcn_readfirstlane(t >> 6);
    const int lane = t & 63;
    const int rlo = lane & 15, khi = lane >> 4;

    f32x4 acc[4][2];
#pragma unroll
    for (int mt = 0; mt < 4; ++mt)
#pragma unroll
        for (int ntl = 0; ntl < 2; ++ntl)
#pragma unroll
            for (int q = 0; q < 4; ++q) acc[mt][ntl][q] = 0.f;

    auto build = [&](int s, unsigned int pk[8]) {
        const int h = s >> 1;
        const int k0 = s << 6;
        float xa[FIN];
#pragma unroll
        for (int f = 0; f < FIN; ++f) xa[f] = xagg_s[row * 91 + h * FIN + f];
        const float* w1s = W1 + (size_t)(k0 + wvu * 16);
        const float* b1s = b1 + (k0 + wvu * 16);
        float z[16];
#pragma unroll
        for (int c = 0; c < 16; ++c) z[c] = b1s[c];
#pragma unroll
        for (int f = 0; f < FIN; ++f)
#pragma unroll
            for (int c = 0; c < 16; ++c)
                z[c] = fmaf(xa[f], w1s[(size_t)f * KK + c], z[c]);
#pragma unroll
        for (int p = 0; p < 8; ++p) {
            float lo = z[2 * p], hi = z[2 * p + 1];
            lo = lo > 0.f ? lo : __expf(lo) - 1.f;
            hi = hi > 0.f ? hi : __expf(hi) - 1.f;
            pk[p] = (unsigned int)f2bf(lo) | ((unsigned int)f2bf(hi) << 16);
        }
    };
    auto writeXs = [&](int buf, const unsigned int pk[8]) {
#pragma unroll
        for (int j = 0; j < 2; ++j) {
            int g = wvu * 2 + j;
            uint4 v = make_uint4(pk[j * 4 + 0], pk[j * 4 + 1], pk[j * 4 + 2], pk[j * 4 + 3]);
            *(uint4*)&Xs[buf][row * 64 + ((g ^ (row & 7)) << 3)] = v;
        }
    };

    __syncthreads();                     // xagg_s staged
    unsigned int pk0[8];
    build(0, pk0);
    writeXs(0, pk0);
    __syncthreads();

    for (int s = 0; s < 20; ++s) {
        const int cur = s & 1;
        short8v bfr[2][2];
#pragma unroll
        for (int ks = 0; ks < 2; ++ks)
#pragma unroll
            for (int ntl = 0; ntl < 2; ++ntl) {
                const int ktabs = s * 2 + ks;
                const int nt = wvu * 2 + ntl;
                bfr[ks][ntl] = *(const short8v*)&W2p[(((size_t)ktabs * 8 + nt) * 64 + lane) * 8];
            }
        unsigned int pn[8];
        if (s < 19) build(s + 1, pn);
#pragma unroll
        for (int ks = 0; ks < 2; ++ks) {
#pragma unroll
            for (int mt = 0; mt < 4; ++mt) {
                const int row2 = mt * 16 + rlo;
                const int gk = ks * 4 + khi;
                short8v af = *(const short8v*)&Xs[cur][row2 * 64 + ((gk ^ (row2 & 7)) << 3)];
                acc[mt][0] = __builtin_amdgcn_mfma_f32_16x16x32_bf16(af, bfr[ks][0], acc[mt][0], 0, 0, 0);
                acc[mt][1] = __builtin_amdgcn_mfma_f32_16x16x32_bf16(af, bfr[ks][1], acc[mt][1], 0, 0, 0);
            }
        }
        if (s < 19) writeXs(cur ^ 1, pn);
        __syncthreads();
    }

    // C write: col = lane&15, row = (lane>>4)*4 + reg
#pragma unroll
    for (int mt = 0; mt < 4; ++mt)
#pragma unroll
        for (int ntl = 0; ntl < 2; ++ntl)
#pragma unroll
            for (int q = 0; q < 4; ++q) {
                int r2 = n0 + mt * 16 + khi * 4 + q;
                int c2 = wvu * 32 + ntl * 16 + rlo;
                h2[(size_t)r2 * DD + c2] = acc[mt][ntl][q];
            }

    // fused alpha2: as2[n] = h2[n,:]·a_src2, ad2[n] = h2[n,:]·a_dst2
    float sp[16], dp[16];
#pragma unroll
    for (int mt = 0; mt < 4; ++mt)
#pragma unroll
        for (int q = 0; q < 4; ++q) {
            float a = 0.f, b = 0.f;
#pragma unroll
            for (int ntl = 0; ntl < 2; ++ntl) {
                int col = wvu * 32 + ntl * 16 + rlo;
                float v = acc[mt][ntl][q];
                a = fmaf(v, a_src2[col], a);
                b = fmaf(v, a_dst2[col], b);
            }
            sp[mt * 4 + q] = a;
            dp[mt * 4 + q] = b;
        }
#pragma unroll
    for (int off = 1; off < 16; off <<= 1) {
#pragma unroll
        for (int i = 0; i < 16; ++i) {
            sp[i] += __shfl_xor(sp[i], off);
            dp[i] += __shfl_xor(dp[i], off);
        }
    }
    if (rlo == 0) {
#pragma unroll
        for (int mt = 0; mt < 4; ++mt)
#pragma unroll
            for (int q = 0; q < 4; ++q) {
                atomicAdd(&as_s[mt * 16 + khi * 4 + q], sp[mt * 4 + q]);
                atomicAdd(&ad_s[mt * 16 + khi * 4 + q], dp[mt * 4 + q]);
            }
    }
    __syncthreads();
    if (t < 64) {
        as2[n0 + t] = as_s[t];
        ad2[n0 + t] = ad_s[t];
    }
}

// ---- layer-2 aggregation (online softmax) -> x2 (coalesced write) -----------
__global__ void agg2_kernel(const int* __restrict__ rowptr, const int* __restrict__ elist,
                            const float* __restrict__ h2,
                            const float* __restrict__ as2, const float* __restrict__ ad2,
                            const float* __restrict__ b2, float* __restrict__ x2) {
    int gid = blockIdx.x * 256 + threadIdx.x;
    int n = gid >> 5, lane = gid & 31;
    if (n >= NN) return;
    int beg = rowptr[n], end = rowptr[n + 1];
    float adn = ad2[n];
    float m = -INFINITY, den = 0.f;
    float4 acc = make_float4(0.f, 0.f, 0.f, 0.f);
    for (int j = beg; j < end; ++j) {
        int s = elist[j];
        float v = lrelu(as2[s] + adn);
        if (v > m) {
            float sc = __expf(m - v);
            den *= sc;
            acc.x *= sc; acc.y *= sc; acc.z *= sc; acc.w *= sc;
            m = v;
        }
        float ex = __expf(v - m);
        den += ex;
        float4 hv = *(const float4*)&h2[(size_t)s * DD + lane * 4];
        acc.x = fmaf(ex, hv.x, acc.x);
        acc.y = fmaf(ex, hv.y, acc.y);
        acc.z = fmaf(ex, hv.z, acc.z);
        acc.w = fmaf(ex, hv.w, acc.w);
    }
    float inv = 1.f / (den + 1e-16f);
    float4 bv = *(const float4*)&b2[lane * 4];
    float4 r;
    r.x = eluf(acc.x * inv + bv.x);
    r.y = eluf(acc.y * inv + bv.y);
    r.z = eluf(acc.z * inv + bv.z);
    r.w = eluf(acc.w * inv + bv.w);
    *(float4*)&x2[(size_t)n * DD + lane * 4] = r;
}

// ---- pooling: one block per graph over its contiguous node range ------------
__global__ void pool_kernel(const int* __restrict__ gptr, const float* __restrict__ x2,
                            float* __restrict__ pooled) {
    int g = blockIdx.x;
    int c = threadIdx.x;          // 128 channels
    int beg = gptr[g], end = gptr[g + 1];
    float v = -INFINITY;
    for (int n = beg; n < end; ++n)
        v = fmaxf(v, x2[(size_t)n * DD + c]);
    if (beg == end) v = 0.f;      // empty graph -> 0 (isfinite guard)
    pooled[g * DD + c] = v;
}

// ---- out = relu(pooled @ Wfc + bfc) -----------------------------------------
__global__ void final_kernel(const float* __restrict__ pooled, const float* __restrict__ Wfc,
                             const float* __restrict__ bfc, float* __restrict__ out) {
    int idx = blockIdx.x * 256 + threadIdx.x;   // NG*DD
    int g = idx >> 7, c = idx & 127;
    float acc = bfc[c];
#pragma unroll 8
    for (int k = 0; k < DD; ++k)
        acc = fmaf(pooled[g * DD + k], Wfc[k * DD + c], acc);
    out[idx] = acc > 0.f ? acc : 0.f;
}

extern "C" void kernel_launch(void* const* d_in, const int* in_sizes, int n_in,
                              void* d_out, int out_size, void* d_ws, size_t ws_size,
                              hipStream_t stream) {
    const float* x      = (const float*)d_in[0];
    const int*   ei     = (const int*)d_in[1];
    const int*   batch  = (const int*)d_in[3];
    const float* W1     = (const float*)d_in[4];
    const float* a_src1 = (const float*)d_in[5];
    const float* a_dst1 = (const float*)d_in[6];
    const float* b1     = (const float*)d_in[7];
    const float* W2     = (const float*)d_in[8];
    const float* a_src2 = (const float*)d_in[9];
    const float* a_dst2 = (const float*)d_in[10];
    const float* b2     = (const float*)d_in[11];
    const float* Wfc    = (const float*)d_in[12];
    const float* bfc    = (const float*)d_in[13];
    float* out = (float*)d_out;

    // workspace layout — ~100 MB total
    float* wsf    = (float*)d_ws;
    float* ws1    = wsf;                                   // 96
    float* wd1    = ws1 + 96;                              // 96
    float* as1    = wd1 + 96;                              // NN*H1
    float* ad1    = as1 + (size_t)NN * H1;                 // NN*H1
    float* xaggn  = ad1 + (size_t)NN * H1;                 // NN*H1*FIN
    float* h2     = xaggn + (size_t)NN * H1 * FIN;         // NN*DD
    float* as2    = h2 + (size_t)NN * DD;                  // NN
    float* ad2    = as2 + NN;                              // NN
    float* x2     = ad2 + NN;                              // NN*DD
    float* pooled = x2 + (size_t)NN * DD;                  // NG*DD
    int*   deg    = (int*)(pooled + (size_t)NG * DD);      // NN
    int*   rowptr = deg + NN;                              // NN+1
    int*   cursor = rowptr + NN + 1;                       // NN
    int*   elist  = cursor + NN;                           // ET
    int*   gptr   = elist + ET;                            // NG+1
    size_t off = (size_t)((char*)(gptr + NG + 1) - (char*)d_ws);
    off = (off + 15) & ~(size_t)15;
    unsigned short* W2p = (unsigned short*)((char*)d_ws + off);  // KK*DD bf16

    prep_kernel   <<<1, 128, 0, stream>>>(W1, a_src1, a_dst1, ws1, wd1);
    packW2_kernel <<<(KK * DD + 255) / 256, 256, 0, stream>>>(W2, W2p);
    alpha1_kernel <<<NN / 256, 256, 0, stream>>>(x, ws1, wd1, as1, ad1, deg);
    count_kernel  <<<(ET + 255) / 256, 256, 0, stream>>>(ei, deg);
    scan_kernel   <<<1, 1024, 0, stream>>>(deg, rowptr, cursor);
    scatter_kernel<<<(ET + 255) / 256, 256, 0, stream>>>(ei, cursor, elist);
    gptr_kernel   <<<NN / 256, 256, 0, stream>>>(batch, gptr);
    agg1_kernel   <<<(NN * H1 + 255) / 256, 256, 0, stream>>>(rowptr, elist, x, as1, ad1, xaggn);
    h2_gemm       <<<NN / 64, 256, 0, stream>>>(xaggn, W1, b1, W2p, a_src2, a_dst2, h2, as2, ad2);
    agg2_kernel   <<<(NN * 32) / 256, 256, 0, stream>>>(rowptr, elist, h2, as2, ad2, b2, x2);
    pool_kernel   <<<NG, 128, 0, stream>>>(gptr, x2, pooled);
    final_kernel  <<<(NG * DD) / 256, 256, 0, stream>>>(pooled, Wfc, bfc, out);
}